// Round 5
// baseline (559.931 us; speedup 1.0000x reference)
//
#include <hip/hip_runtime.h>
#include <hip/hip_cooperative_groups.h>

namespace cg = cooperative_groups;

#define E_EDGES 800000
#define NN 50000
#define NBLK 256
#define NTHR 512
#define GT (NBLK * NTHR)
#define OUT_STRIDE 288

typedef __bf16 bf16;
typedef bf16 bf16x8 __attribute__((ext_vector_type(8)));
typedef float floatx4 __attribute__((ext_vector_type(4)));
typedef unsigned short ushort8v __attribute__((ext_vector_type(8)));

__device__ __forceinline__ unsigned short f2bf(float f){
    unsigned u = __float_as_uint(f);
    u += 0x7fffu + ((u >> 16) & 1u);   // RNE
    return (unsigned short)(u >> 16);
}
__device__ __forceinline__ unsigned pack2bf(float a, float b){
    return (unsigned)f2bf(a) | ((unsigned)f2bf(b) << 16);
}
// monotone float<->uint for atomicMax/Min
__device__ __forceinline__ unsigned encf(float f){
    unsigned u = __float_as_uint(f);
    return (u & 0x80000000u) ? ~u : (u | 0x80000000u);
}
__device__ __forceinline__ float decf(unsigned u){
    return __uint_as_float((u & 0x80000000u) ? (u ^ 0x80000000u) : ~u);
}
__device__ __forceinline__ floatx4 mfma16(ushort8v a, ushort8v b, floatx4 c){
    return __builtin_amdgcn_mfma_f32_16x16x32_bf16(
        __builtin_bit_cast(bf16x8, a), __builtin_bit_cast(bf16x8, b), c, 0, 0, 0);
}
__device__ __forceinline__ void flush_run(float* out, int node, float s, float mx, float mn, int lane){
    float* sp = out + (long)node * OUT_STRIDE + 64;
    atomicAdd(sp + lane, s);
    atomicMax((unsigned*)sp + 64 + lane, encf(mx));
    atomicMin((unsigned*)sp + 128 + lane, encf(mn));
}

// LDS: [0,69632) 8 wave-bufs of 8704B | [69632,151552) weight frags | [151552,152832) biases
#define SM_BYTES 152832
#define SM_WOFF  69632
#define SM_BOFF  151552

__global__ __launch_bounds__(NTHR, 2) void fused_kernel(
    const float* __restrict__ x, const int* __restrict__ ei,
    const float* __restrict__ u, const int* __restrict__ batch,
    const float* __restrict__ W1, const float* __restrict__ b1,
    const float* __restrict__ W2, const float* __restrict__ b2,
    const float* __restrict__ W3, const float* __restrict__ b3,
    float* __restrict__ out, unsigned char* __restrict__ ws)
{
    __shared__ __align__(16) unsigned char smem[SM_BYTES];

    // workspace partition
    unsigned short* wp     = (unsigned short*)ws;              //    81,920 B
    int*            cnt    = (int*)(ws + 81920);               //   200,000 B
    int*            off    = (int*)(ws + 281920);              //   200,000 B
    int2*           enodes = (int2*)(ws + 481920);             // 6,400,000 B
    unsigned short* xbf    = (unsigned short*)(ws + 6881920);  // 6,400,000 B
    int*            bsum   = (int*)enodes;                     // reuse: dead before scatter writes

    cg::grid_group grid = cg::this_grid();
    const int tid  = threadIdx.x;
    const int gtid = blockIdx.x * NTHR + tid;

    // ---------- P0: zero cnt | init out accum | x->bf16 | prepack weights ----------
    for (int i = gtid; i < 12500; i += GT)
        ((int4*)cnt)[i] = make_int4(0, 0, 0, 0);
    for (int i = gtid; i < 2400000; i += GT){
        int row = i / 48, q = i % 48;   // [sum 0..16 | max 16..32 | min 32..48] uint4 units
        uint4 val = (q < 32) ? make_uint4(0u, 0u, 0u, 0u)
                             : make_uint4(~0u, ~0u, ~0u, ~0u);
        ((uint4*)out)[(long)row * 72 + 16 + q] = val;
    }
    for (int i = gtid; i < 800000; i += GT){
        float4 v = ((const float4*)x)[i];
        ushort4 o; o.x = f2bf(v.x); o.y = f2bf(v.y); o.z = f2bf(v.z); o.w = f2bf(v.w);
        ((ushort4*)xbf)[i] = o;
    }
    for (int i = gtid; i < 40960; i += GT){
        // A-fragment pack: wp[f*8+j] = W[kc*32+(lane>>4)*8+j][nt*16+(lane&15)]
        const float* W; int N; int idx;
        if (i < 16384)      { W = W1; N = 128; idx = i; }
        else if (i < 32768) { W = W2; N = 128; idx = i - 16384; }
        else                { W = W3; N = 64;  idx = i - 32768; }
        int j = idx & 7, lane = (idx >> 3) & 63, kc = (idx >> 9) & 3, nt = idx >> 11;
        wp[i] = f2bf(W[(kc * 32 + ((lane >> 4) & 3) * 8 + j) * N + nt * 16 + (lane & 15)]);
    }
    grid.sync();

    // ---------- P1: histogram ----------
    for (int e = gtid; e < E_EDGES; e += GT)
        atomicAdd(&cnt[ei[E_EDGES + e]], 1);
    grid.sync();

    // ---------- P2a: block-local exclusive scan (196 nodes/block) ----------
    {
        int* s = (int*)smem;
        int node = blockIdx.x * 196 + tid;
        int val = 0;
        if (tid < 196 && node < NN) val = cnt[node];
        if (tid < 256) s[tid] = (tid < 196) ? val : 0;
        __syncthreads();
        for (int d = 1; d < 256; d <<= 1){
            int t = 0;
            if (tid < 256 && tid >= d) t = s[tid - d];
            __syncthreads();
            if (tid < 256) s[tid] += t;
            __syncthreads();
        }
        if (tid < 196 && node < NN) off[node] = s[tid] - val;
        if (tid == 0) bsum[blockIdx.x] = s[255];
    }
    grid.sync();

    // ---------- P2b: add block bases (each block scans all 256 bsums) ----------
    {
        int* s = (int*)smem;
        if (tid < 256) s[tid] = bsum[tid];
        __syncthreads();
        for (int d = 1; d < 256; d <<= 1){
            int t = 0;
            if (tid < 256 && tid >= d) t = s[tid - d];
            __syncthreads();
            if (tid < 256) s[tid] += t;
            __syncthreads();
        }
        int base = (blockIdx.x == 0) ? 0 : s[blockIdx.x - 1];
        int node = blockIdx.x * 196 + tid;
        if (tid < 196 && node < NN) off[node] += base;
    }
    grid.sync();

    // ---------- P3: scatter sorted edge descriptors ----------
    for (int e = gtid; e < E_EDGES; e += GT){
        int c = ei[E_EDGES + e], r = ei[e];
        int pos = atomicAdd(&off[c], 1);
        enodes[pos] = make_int2(r, c);
    }
    grid.sync();

    // ---------- stage weights + biases into LDS ----------
    {
        uint4* dst = (uint4*)(smem + SM_WOFF);
        const uint4* src = (const uint4*)wp;
        for (int i = tid; i < 5120; i += NTHR) dst[i] = src[i];
        float* bl = (float*)(smem + SM_BOFF);
        for (int i = tid; i < 128; i += NTHR) bl[i] = b1[i];
        for (int i = tid; i < 128; i += NTHR) bl[128 + i] = b2[i];
        for (int i = tid; i < 64;  i += NTHR) bl[256 + i] = b3[i];
    }
    __syncthreads();

    // ---------- P4: edge MLP, 32 edges per wave-tile ----------
    {
        const int lane = tid & 63;
        const int w    = tid >> 6;
        const int quad = lane >> 4;
        const int ln   = lane & 15;
        unsigned short* wbuf = (unsigned short*)(smem + w * 8704);  // 32 rows x 136 u16
        float* Tf = (float*)wbuf;                                    // 64 rows x 33 f32 (8448B)
        const ushort8v* wfrag = (const ushort8v*)(smem + SM_WOFF);
        const float* bl = (const float*)(smem + SM_BOFF);

        for (int g = blockIdx.x * 8 + w; g < 25000; g += 2048){
            const int ebase = g * 32;
            int2 ed0 = enodes[ebase + ln];
            int2 ed1 = enodes[ebase + 16 + ln];

            // layer-1 B-frags (activations) straight from global bf16 x rows
            const ushort8v* r0 = (const ushort8v*)(xbf + (long)ed0.x * 64);
            const ushort8v* c0 = (const ushort8v*)(xbf + (long)ed0.y * 64);
            const ushort8v* r1 = (const ushort8v*)(xbf + (long)ed1.x * 64);
            const ushort8v* c1 = (const ushort8v*)(xbf + (long)ed1.y * 64);
            ushort8v B0[4] = { r0[quad], r0[4 + quad], c0[quad], c0[4 + quad] };
            ushort8v B1[4] = { r1[quad], r1[4 + quad], c1[quad], c1[4 + quad] };

            // ---- layer 1: D[och][edge], write bf16 rows [edge][och] ----
#pragma unroll
            for (int nt = 0; nt < 8; nt++){
                floatx4 bini = *(const floatx4*)(bl + nt * 16 + quad * 4);
                floatx4 a0 = bini, a1 = bini;
#pragma unroll
                for (int kc = 0; kc < 4; kc++){
                    ushort8v Af = wfrag[(nt * 4 + kc) * 64 + lane];
                    a0 = mfma16(Af, B0[kc], a0);
                    a1 = mfma16(Af, B1[kc], a1);
                }
                uint2 p0, p1;
                p0.x = pack2bf(fmaxf(a0[0], 0.f), fmaxf(a0[1], 0.f));
                p0.y = pack2bf(fmaxf(a0[2], 0.f), fmaxf(a0[3], 0.f));
                p1.x = pack2bf(fmaxf(a1[0], 0.f), fmaxf(a1[1], 0.f));
                p1.y = pack2bf(fmaxf(a1[2], 0.f), fmaxf(a1[3], 0.f));
                int col = nt * 16 + quad * 4;
                *(uint2*)(wbuf + ln * 136 + col)        = p0;
                *(uint2*)(wbuf + (16 + ln) * 136 + col) = p1;
            }

            // ---- layer 2: preload B-frags, in-place update ----
            ushort8v H0[4], H1[4];
#pragma unroll
            for (int kc = 0; kc < 4; kc++){
                H0[kc] = *(const ushort8v*)(wbuf + ln * 136 + kc * 32 + quad * 8);
                H1[kc] = *(const ushort8v*)(wbuf + (16 + ln) * 136 + kc * 32 + quad * 8);
            }
#pragma unroll
            for (int nt = 0; nt < 8; nt++){
                floatx4 bini = *(const floatx4*)(bl + 128 + nt * 16 + quad * 4);
                floatx4 a0 = bini, a1 = bini;
#pragma unroll
                for (int kc = 0; kc < 4; kc++){
                    ushort8v Af = wfrag[2048 + (nt * 4 + kc) * 64 + lane];
                    a0 = mfma16(Af, H0[kc], a0);
                    a1 = mfma16(Af, H1[kc], a1);
                }
                uint2 p0, p1;
                p0.x = pack2bf(fmaxf(a0[0], 0.f), fmaxf(a0[1], 0.f));
                p0.y = pack2bf(fmaxf(a0[2], 0.f), fmaxf(a0[3], 0.f));
                p1.x = pack2bf(fmaxf(a1[0], 0.f), fmaxf(a1[1], 0.f));
                p1.y = pack2bf(fmaxf(a1[2], 0.f), fmaxf(a1[3], 0.f));
                int col = nt * 16 + quad * 4;
                *(uint2*)(wbuf + ln * 136 + col)        = p0;
                *(uint2*)(wbuf + (16 + ln) * 136 + col) = p1;
            }

            // ---- layer 3: preload B-frags, write f32 T[och][edge] (LD=33) ----
            ushort8v G0[4], G1[4];
#pragma unroll
            for (int kc = 0; kc < 4; kc++){
                G0[kc] = *(const ushort8v*)(wbuf + ln * 136 + kc * 32 + quad * 8);
                G1[kc] = *(const ushort8v*)(wbuf + (16 + ln) * 136 + kc * 32 + quad * 8);
            }
#pragma unroll
            for (int nt = 0; nt < 4; nt++){
                floatx4 bini = *(const floatx4*)(bl + 256 + nt * 16 + quad * 4);
                floatx4 a0 = bini, a1 = bini;
#pragma unroll
                for (int kc = 0; kc < 4; kc++){
                    ushort8v Af = wfrag[4096 + (nt * 4 + kc) * 64 + lane];
                    a0 = mfma16(Af, G0[kc], a0);
                    a1 = mfma16(Af, G1[kc], a1);
                }
                int och = nt * 16 + quad * 4;
#pragma unroll
                for (int r = 0; r < 4; r++){
                    Tf[(och + r) * 33 + ln]      = a0[r];
                    Tf[(och + r) * 33 + 16 + ln] = a1[r];
                }
            }

            // ---- epilogue: lane = channel, run-reduce over 32 sorted edges ----
            float v[32];
#pragma unroll
            for (int j = 0; j < 32; j++) v[j] = Tf[lane * 33 + j];
            int cn0 = ed0.y, cn1 = ed1.y;
            int cur = __builtin_amdgcn_readlane(cn0, 0);
            float s = v[0], mx = v[0], mn = v[0];
#pragma unroll
            for (int j = 1; j < 32; j++){
                int nj = (j < 16) ? __builtin_amdgcn_readlane(cn0, j)
                                  : __builtin_amdgcn_readlane(cn1, j - 16);
                if (nj != cur){
                    flush_run(out, cur, s, mx, mn, lane);
                    cur = nj; s = v[j]; mx = v[j]; mn = v[j];
                } else {
                    s += v[j]; mx = fmaxf(mx, v[j]); mn = fminf(mn, v[j]);
                }
            }
            flush_run(out, cur, s, mx, mn, lane);
        }
    }
    grid.sync();

    // ---------- P5: finalize ----------
    for (long i = gtid; i < (long)NN * 72; i += GT){
        int ndx = (int)(i / 72);
        int q   = (int)(i % 72);
        float4 res;
        if (q < 16) {
            res = ((const float4*)(x + (long)ndx * 64))[q];
        } else if (q < 32) {
            float4 sv = ((const float4*)out)[i];
            int k = cnt[ndx];
            float inv = 1.f / (float)(k > 0 ? k : 1);
            res.x = sv.x * inv; res.y = sv.y * inv; res.z = sv.z * inv; res.w = sv.w * inv;
        } else if (q < 64) {
            uint4 e = ((const uint4*)out)[i];
            bool ne = cnt[ndx] > 0;
            res.x = ne ? decf(e.x) : 0.f; res.y = ne ? decf(e.y) : 0.f;
            res.z = ne ? decf(e.z) : 0.f; res.w = ne ? decf(e.w) : 0.f;
        } else {
            res = ((const float4*)(u + (long)batch[ndx] * 32))[q - 64];
        }
        ((float4*)out)[i] = res;
    }
}

extern "C" void kernel_launch(void* const* d_in, const int* in_sizes, int n_in,
                              void* d_out, int out_size, void* d_ws, size_t ws_size,
                              hipStream_t stream)
{
    const float* x     = (const float*)d_in[0];
    const int*   ei    = (const int*)d_in[1];
    // d_in[2] = edge_attr (unused)
    const float* u     = (const float*)d_in[3];
    const int*   batch = (const int*)d_in[4];
    const float* W1    = (const float*)d_in[5];
    const float* b1    = (const float*)d_in[6];
    const float* W2    = (const float*)d_in[7];
    const float* b2    = (const float*)d_in[8];
    const float* W3    = (const float*)d_in[9];
    const float* b3    = (const float*)d_in[10];
    float* out = (float*)d_out;
    unsigned char* ws = (unsigned char*)d_ws;

    void* args[] = { &x, &ei, &u, &batch, &W1, &b1, &W2, &b2, &W3, &b3, &out, &ws };
    hipLaunchCooperativeKernel(reinterpret_cast<void*>(fused_kernel),
                               dim3(NBLK), dim3(NTHR), args, 0, stream);
}

// Round 7
// 322.735 us; speedup vs baseline: 1.7350x; 1.7350x over previous
//
#include <hip/hip_runtime.h>

#define E_EDGES 800000
#define NN 50000
#define OUT_STRIDE 288

typedef __bf16 bf16;
typedef bf16 bf16x8 __attribute__((ext_vector_type(8)));
typedef float floatx4 __attribute__((ext_vector_type(4)));
typedef unsigned short ushort8v __attribute__((ext_vector_type(8)));

__device__ __forceinline__ unsigned short f2bf(float f){
    unsigned u = __float_as_uint(f);
    u += 0x7fffu + ((u >> 16) & 1u);   // RNE
    return (unsigned short)(u >> 16);
}
__device__ __forceinline__ unsigned pack2bf(float a, float b){
    return (unsigned)f2bf(a) | ((unsigned)f2bf(b) << 16);
}
// monotone float<->uint for atomicMax/Min
__device__ __forceinline__ unsigned encf(float f){
    unsigned u = __float_as_uint(f);
    return (u & 0x80000000u) ? ~u : (u | 0x80000000u);
}
__device__ __forceinline__ float decf(unsigned u){
    return __uint_as_float((u & 0x80000000u) ? (u ^ 0x80000000u) : ~u);
}
__device__ __forceinline__ floatx4 mfma16(ushort8v a, ushort8v b, floatx4 c){
    return __builtin_amdgcn_mfma_f32_16x16x32_bf16(
        __builtin_bit_cast(bf16x8, a), __builtin_bit_cast(bf16x8, b), c, 0, 0, 0);
}
__device__ __forceinline__ void flush_run(float* out, int node, float s, float mx, float mn, int lane){
    float* sp = out + (long)node * OUT_STRIDE + 64;
    atomicAdd(sp + lane, s);
    atomicMax((unsigned*)sp + 64 + lane, encf(mx));
    atomicMin((unsigned*)sp + 128 + lane, encf(mn));
}

// ---------------- setup: zero cnt | init out accum | x->bf16 | prepack weights ----------------
#define ZC_N   12500
#define INIT_N 2400000
#define XBF_N  800000
#define PK_N   40960
#define SETUP_TOTAL (ZC_N + INIT_N + XBF_N + PK_N)

__global__ void setup_kernel(const float* __restrict__ x,
                             const float* __restrict__ W1, const float* __restrict__ W2,
                             const float* __restrict__ W3,
                             unsigned short* __restrict__ wp, unsigned short* __restrict__ xbf,
                             int* __restrict__ cnt, float* __restrict__ out)
{
    int i = blockIdx.x * blockDim.x + threadIdx.x;
    if (i < ZC_N) {
        ((int4*)cnt)[i] = make_int4(0, 0, 0, 0);
        return;
    }
    i -= ZC_N;
    if (i < INIT_N) {
        // out row: [x 0..16 | sum 16..32 | max 32..48 | min 48..64 | u 64..72] uint4 units
        int row = i / 48, q = i % 48;
        uint4 val = (q < 32) ? make_uint4(0u, 0u, 0u, 0u)
                             : make_uint4(~0u, ~0u, ~0u, ~0u);
        ((uint4*)out)[(long)row * 72 + 16 + q] = val;
        return;
    }
    i -= INIT_N;
    if (i < XBF_N) {
        float4 v = ((const float4*)x)[i];
        ushort4 o; o.x = f2bf(v.x); o.y = f2bf(v.y); o.z = f2bf(v.z); o.w = f2bf(v.w);
        ((ushort4*)xbf)[i] = o;
        return;
    }
    i -= XBF_N;
    if (i < PK_N) {
        // A-fragment pack (weights as A): wp[f*8+j] = W[kc*32+quad*8+j][nt*16+ln]
        const float* W; int N; int idx;
        if (i < 16384)      { W = W1; N = 128; idx = i; }
        else if (i < 32768) { W = W2; N = 128; idx = i - 16384; }
        else                { W = W3; N = 64;  idx = i - 32768; }
        int j = idx & 7, lane = (idx >> 3) & 63, kc = (idx >> 9) & 3, nt = idx >> 11;
        wp[i] = f2bf(W[(kc * 32 + ((lane >> 4) & 3) * 8 + j) * N + nt * 16 + (lane & 15)]);
    }
}

// ---------------- counting sort by destination ----------------
__global__ void hist_kernel(const int* __restrict__ ei, int* __restrict__ cnt){
    int e = blockIdx.x * blockDim.x + threadIdx.x;
    if (e < E_EDGES) atomicAdd(&cnt[ei[E_EDGES + e]], 1);
}

// scanA: 256 blocks x 256 thr, 196 nodes/block -> local exclusive + block sums
__global__ void scanA_kernel(const int* __restrict__ cnt, int* __restrict__ off,
                             int* __restrict__ bsum){
    __shared__ int s[256];
    int tid = threadIdx.x;
    int node = blockIdx.x * 196 + tid;
    int val = (tid < 196 && node < NN) ? cnt[node] : 0;
    s[tid] = val;
    __syncthreads();
    for (int d = 1; d < 256; d <<= 1){
        int t = (tid >= d) ? s[tid - d] : 0;
        __syncthreads();
        s[tid] += t;
        __syncthreads();
    }
    if (tid < 196 && node < NN) off[node] = s[tid] - val;  // local exclusive
    if (tid == 255) bsum[blockIdx.x] = s[255];             // block total
}

// scanB: 1 block x 256 thr, exclusive-scan bsum -> bbase
__global__ void scanB_kernel(const int* __restrict__ bsum, int* __restrict__ bbase){
    __shared__ int s[256];
    int tid = threadIdx.x;
    int val = bsum[tid];
    s[tid] = val;
    __syncthreads();
    for (int d = 1; d < 256; d <<= 1){
        int t = (tid >= d) ? s[tid - d] : 0;
        __syncthreads();
        s[tid] += t;
        __syncthreads();
    }
    bbase[tid] = s[tid] - val;  // exclusive
}

// scanC: off[n] += bbase[n/196]
__global__ void scanC_kernel(int* __restrict__ off, const int* __restrict__ bbase){
    int n = blockIdx.x * blockDim.x + threadIdx.x;
    if (n < NN) off[n] += bbase[n / 196];
}

__global__ void scatter_kernel(const int* __restrict__ ei, int* __restrict__ off,
                               int2* __restrict__ enodes){
    int e = blockIdx.x * blockDim.x + threadIdx.x;
    if (e >= E_EDGES) return;
    int c = ei[E_EDGES + e], r = ei[e];
    int pos = atomicAdd(&off[c], 1);
    enodes[pos] = make_int2(r, c);
}

// ---------------- edge MLP: 32 edges per wave-tile, barrier-free ----------------
__global__ __launch_bounds__(256, 4) void edge_mlp_kernel(
    const unsigned short* __restrict__ xbf, const int2* __restrict__ enodes,
    const unsigned short* __restrict__ wp,
    const float* __restrict__ b1, const float* __restrict__ b2, const float* __restrict__ b3,
    float* __restrict__ out)
{
    __shared__ __align__(16) unsigned char smem[4 * 8704];

    const int tid  = threadIdx.x;
    const int lane = tid & 63;
    const int w    = tid >> 6;
    const int quad = lane >> 4;
    const int ln   = lane & 15;
    unsigned short* wbuf = (unsigned short*)(smem + w * 8704);  // 32 rows x 136 u16
    float* Tf = (float*)wbuf;                                    // 64 rows x 33 f32
    const ushort8v* wpv = (const ushort8v*)wp;

    const int g = blockIdx.x * 4 + w;       // tile id, 25000 total
    const int ebase = g * 32;
    int2 ed0 = enodes[ebase + ln];
    int2 ed1 = enodes[ebase + 16 + ln];

    const ushort8v* r0 = (const ushort8v*)(xbf + (long)ed0.x * 64);
    const ushort8v* c0 = (const ushort8v*)(xbf + (long)ed0.y * 64);
    const ushort8v* r1 = (const ushort8v*)(xbf + (long)ed1.x * 64);
    const ushort8v* c1 = (const ushort8v*)(xbf + (long)ed1.y * 64);
    ushort8v B0[4] = { r0[quad], r0[4 + quad], c0[quad], c0[4 + quad] };
    ushort8v B1[4] = { r1[quad], r1[4 + quad], c1[quad], c1[4 + quad] };

    // ---- layer 1: D[och][edge] -> wbuf[edge][och] bf16 ----
#pragma unroll
    for (int nt = 0; nt < 8; nt++){
        floatx4 bini = *(const floatx4*)(b1 + nt * 16 + quad * 4);
        floatx4 a0 = bini, a1 = bini;
#pragma unroll
        for (int kc = 0; kc < 4; kc++){
            ushort8v Af = wpv[(nt * 4 + kc) * 64 + lane];
            a0 = mfma16(Af, B0[kc], a0);
            a1 = mfma16(Af, B1[kc], a1);
        }
        uint2 p0, p1;
        p0.x = pack2bf(fmaxf(a0[0], 0.f), fmaxf(a0[1], 0.f));
        p0.y = pack2bf(fmaxf(a0[2], 0.f), fmaxf(a0[3], 0.f));
        p1.x = pack2bf(fmaxf(a1[0], 0.f), fmaxf(a1[1], 0.f));
        p1.y = pack2bf(fmaxf(a1[2], 0.f), fmaxf(a1[3], 0.f));
        int col = nt * 16 + quad * 4;
        *(uint2*)(wbuf + ln * 136 + col)        = p0;
        *(uint2*)(wbuf + (16 + ln) * 136 + col) = p1;
    }

    // ---- layer 2: preload B-frags, in-place ----
    ushort8v H0[4], H1[4];
#pragma unroll
    for (int kc = 0; kc < 4; kc++){
        H0[kc] = *(const ushort8v*)(wbuf + ln * 136 + kc * 32 + quad * 8);
        H1[kc] = *(const ushort8v*)(wbuf + (16 + ln) * 136 + kc * 32 + quad * 8);
    }
#pragma unroll
    for (int nt = 0; nt < 8; nt++){
        floatx4 bini = *(const floatx4*)(b2 + nt * 16 + quad * 4);
        floatx4 a0 = bini, a1 = bini;
#pragma unroll
        for (int kc = 0; kc < 4; kc++){
            ushort8v Af = wpv[2048 + (nt * 4 + kc) * 64 + lane];
            a0 = mfma16(Af, H0[kc], a0);
            a1 = mfma16(Af, H1[kc], a1);
        }
        uint2 p0, p1;
        p0.x = pack2bf(fmaxf(a0[0], 0.f), fmaxf(a0[1], 0.f));
        p0.y = pack2bf(fmaxf(a0[2], 0.f), fmaxf(a0[3], 0.f));
        p1.x = pack2bf(fmaxf(a1[0], 0.f), fmaxf(a1[1], 0.f));
        p1.y = pack2bf(fmaxf(a1[2], 0.f), fmaxf(a1[3], 0.f));
        int col = nt * 16 + quad * 4;
        *(uint2*)(wbuf + ln * 136 + col)        = p0;
        *(uint2*)(wbuf + (16 + ln) * 136 + col) = p1;
    }

    // ---- layer 3: f32 T[och][edge], LD=33 ----
    ushort8v G0[4], G1[4];
#pragma unroll
    for (int kc = 0; kc < 4; kc++){
        G0[kc] = *(const ushort8v*)(wbuf + ln * 136 + kc * 32 + quad * 8);
        G1[kc] = *(const ushort8v*)(wbuf + (16 + ln) * 136 + kc * 32 + quad * 8);
    }
#pragma unroll
    for (int nt = 0; nt < 4; nt++){
        floatx4 bini = *(const floatx4*)(b3 + nt * 16 + quad * 4);
        floatx4 a0 = bini, a1 = bini;
#pragma unroll
        for (int kc = 0; kc < 4; kc++){
            ushort8v Af = wpv[4096 + (nt * 4 + kc) * 64 + lane];
            a0 = mfma16(Af, G0[kc], a0);
            a1 = mfma16(Af, G1[kc], a1);
        }
        int och = nt * 16 + quad * 4;
#pragma unroll
        for (int r = 0; r < 4; r++){
            Tf[(och + r) * 33 + ln]      = a0[r];
            Tf[(och + r) * 33 + 16 + ln] = a1[r];
        }
    }

    // ---- epilogue: lane = channel, run-reduce over 32 sorted edges ----
    float v[32];
#pragma unroll
    for (int j = 0; j < 32; j++) v[j] = Tf[lane * 33 + j];
    int cn0 = ed0.y, cn1 = ed1.y;
    int cur = __builtin_amdgcn_readlane(cn0, 0);
    float s = v[0], mx = v[0], mn = v[0];
#pragma unroll
    for (int j = 1; j < 32; j++){
        int nj = (j < 16) ? __builtin_amdgcn_readlane(cn0, j)
                          : __builtin_amdgcn_readlane(cn1, j - 16);
        if (nj != cur){
            flush_run(out, cur, s, mx, mn, lane);
            cur = nj; s = v[j]; mx = v[j]; mn = v[j];
        } else {
            s += v[j]; mx = fmaxf(mx, v[j]); mn = fminf(mn, v[j]);
        }
    }
    flush_run(out, cur, s, mx, mn, lane);
}

// ---------------- finalize ----------------
__global__ void finalize_kernel(const float* __restrict__ x, const float* __restrict__ u,
                                const int* __restrict__ batch, const int* __restrict__ cnt,
                                float* __restrict__ out)
{
    long i = (long)blockIdx.x * blockDim.x + threadIdx.x;
    if (i >= (long)NN * 72) return;
    int ndx = (int)(i / 72);
    int q   = (int)(i % 72);
    float4 res;
    if (q < 16) {
        res = ((const float4*)(x + (long)ndx * 64))[q];
    } else if (q < 32) {
        float4 sv = ((const float4*)out)[i];
        int k = cnt[ndx];
        float inv = 1.f / (float)(k > 0 ? k : 1);
        res.x = sv.x * inv; res.y = sv.y * inv; res.z = sv.z * inv; res.w = sv.w * inv;
    } else if (q < 64) {
        uint4 e = ((const uint4*)out)[i];
        bool ne = cnt[ndx] > 0;
        res.x = ne ? decf(e.x) : 0.f; res.y = ne ? decf(e.y) : 0.f;
        res.z = ne ? decf(e.z) : 0.f; res.w = ne ? decf(e.w) : 0.f;
    } else {
        res = ((const float4*)(u + (long)batch[ndx] * 32))[q - 64];
    }
    ((float4*)out)[i] = res;
}

extern "C" void kernel_launch(void* const* d_in, const int* in_sizes, int n_in,
                              void* d_out, int out_size, void* d_ws, size_t ws_size,
                              hipStream_t stream)
{
    const float* x     = (const float*)d_in[0];
    const int*   ei    = (const int*)d_in[1];
    // d_in[2] = edge_attr (unused)
    const float* u     = (const float*)d_in[3];
    const int*   batch = (const int*)d_in[4];
    const float* W1    = (const float*)d_in[5];
    const float* b1    = (const float*)d_in[6];
    const float* W2    = (const float*)d_in[7];
    const float* b2    = (const float*)d_in[8];
    const float* W3    = (const float*)d_in[9];
    const float* b3    = (const float*)d_in[10];
    float* out = (float*)d_out;
    unsigned char* ws = (unsigned char*)d_ws;

    // ws layout (16B-aligned)
    unsigned short* wp     = (unsigned short*)ws;              //    81,920 B
    int*            cnt    = (int*)(ws + 81920);               //   200,000 B
    int*            off    = (int*)(ws + 281920);              //   200,000 B
    int*            bsum   = (int*)(ws + 481920);              //     1,024 B
    int*            bbase  = (int*)(ws + 482944);              //     1,024 B
    int2*           enodes = (int2*)(ws + 483968);             // 6,400,000 B
    unsigned short* xbf    = (unsigned short*)(ws + 6883968);  // 6,400,000 B

    setup_kernel<<<(SETUP_TOTAL + 255) / 256, 256, 0, stream>>>(x, W1, W2, W3, wp, xbf, cnt, out);
    hist_kernel<<<(E_EDGES + 255) / 256, 256, 0, stream>>>(ei, cnt);
    scanA_kernel<<<256, 256, 0, stream>>>(cnt, off, bsum);
    scanB_kernel<<<1, 256, 0, stream>>>(bsum, bbase);
    scanC_kernel<<<(NN + 255) / 256, 256, 0, stream>>>(off, bbase);
    scatter_kernel<<<(E_EDGES + 255) / 256, 256, 0, stream>>>(ei, off, enodes);
    edge_mlp_kernel<<<6250, 256, 0, stream>>>(xbf, enodes, wp, b1, b2, b3, out);
    finalize_kernel<<<(int)(((long)NN * 72 + 255) / 256), 256, 0, stream>>>(x, u, batch, cnt, out);
}